// Round 6
// baseline (906.275 us; speedup 1.0000x reference)
//
#include <hip/hip_runtime.h>
#include <hip/hip_fp16.h>
#include <cstddef>
#include <cstdint>

typedef _Float16 f16;
typedef _Float16 f16x8 __attribute__((ext_vector_type(8)));
typedef _Float16 f16x4 __attribute__((ext_vector_type(4)));
typedef float    f32x4 __attribute__((ext_vector_type(4)));

#define BK 64   // K-tile depth (fp16 elems); 2 MFMA k-steps per tile

// async 16B global->LDS (linear LDS dest = wave-uniform base + lane*16)
__device__ __forceinline__ void gload16(const void* g, void* lds) {
  __builtin_amdgcn_global_load_lds(
      (const __attribute__((address_space(1))) unsigned int*)g,
      (__attribute__((address_space(3))) unsigned int*)lds, 16, 0, 0);
}

// Stage an [R x 64] fp16 tile via global_load_lds. LDS row r holds global
// 8-elem slot s at slot s^(r&7) (rule-21 both-sides swizzle: source address
// pre-swizzled here, reader XORs identically).
template<int R>
__device__ __forceinline__ void stage_f16(f16 (*buf)[BK], const f16* __restrict__ src,
                                          int ld, int w, int lane) {
#pragma unroll
  for (int i = 0; i < R / 32; i++) {
    const int grp  = w * (R / 32) + i;          // wave-uniform
    const int r    = grp * 8 + (lane >> 3);
    const int slot = (lane & 7) ^ (r & 7);
    gload16(src + (size_t)r * ld + slot * 8, &buf[grp * 8][0]);
  }
}

// Reg-staging for f32 sources (T14 issue-early / write-late).
template<int R>
struct RegStage {
  static constexpr int NV = (R == 128) ? 8 : 4;   // float4 loads per thread
  float4 v[NV];
  __device__ __forceinline__ void load(const float* __restrict__ src, int ld, int tid) {
    const int r = (R == 128) ? (tid >> 1) : (tid >> 2);
    const int h = (R == 128) ? (tid & 1) * 32 : (tid & 3) * 16;
    const float* p = src + (size_t)r * ld + h;
#pragma unroll
    for (int j = 0; j < NV; j++) v[j] = ((const float4*)p)[j];
  }
  __device__ __forceinline__ void write(f16 (*buf)[BK], int tid) {
    const int r = (R == 128) ? (tid >> 1) : (tid >> 2);
    const int h = (R == 128) ? (tid & 1) * 32 : (tid & 3) * 16;
#pragma unroll
    for (int g = 0; g < NV / 2; g++) {
      const float4 a = v[g * 2], b = v[g * 2 + 1];
      f16x8 o;
      o[0] = (f16)a.x; o[1] = (f16)a.y; o[2] = (f16)a.z; o[3] = (f16)a.w;
      o[4] = (f16)b.x; o[5] = (f16)b.y; o[6] = (f16)b.z; o[7] = (f16)b.w;
      const int slot = (h / 8 + g) ^ (r & 7);
      *(f16x8*)&buf[r][slot * 8] = o;
    }
  }
};

// ---------------------------------------------------------------------------
// TN GEMM, double-buffered: C[M][N] = A[M][K] @ B[N][K]^T (+bias[n]) (+relu).
// fp16 operands: global_load_lds. f32 operands: reg-stage + cvt.
// Chunked bijective XCD swizzle on (bx,by); requires nxy % 8 == 0.
// ---------------------------------------------------------------------------
template<int BMt, int BNt, typename TA, typename TB, bool BIAS, bool RELU, typename TC>
__global__ __launch_bounds__(256, 2)
void gemm_tn(const TA* __restrict__ A, int lda,
             const TB* __restrict__ B, int ldb,
             TC* __restrict__ C, int ldc,
             const float* __restrict__ bias, int K)
{
  constexpr int MF = BMt / 32;
  constexpr int NF = BNt / 32;
  __shared__ f16 As[2][BMt][BK];
  __shared__ f16 Bs[2][BNt][BK];
  const int tid  = threadIdx.x;
  const int lane = tid & 63;
  const int w    = tid >> 6;
  const int wr   = w >> 1, wc = w & 1;

  const int gx = gridDim.x, nxy = gx * gridDim.y;
  int lin = blockIdx.y * gx + blockIdx.x;
  lin = (lin & 7) * (nxy >> 3) + (lin >> 3);
  const int m0 = (lin % gx) * BMt;
  const int n0 = (lin / gx) * BNt;

  f32x4 acc[MF][NF] = {};
  RegStage<BMt> ra;   // dead when TA == f16
  RegStage<BNt> rb;   // dead when TB == f16

  auto stage_issue = [&](int buf, int k0) {
    if constexpr (sizeof(TA) == 2)
      stage_f16<BMt>(As[buf], (const f16*)A + (size_t)m0 * lda + k0, lda, w, lane);
    else
      ra.load((const float*)A + (size_t)m0 * lda + k0, lda, tid);
    if constexpr (sizeof(TB) == 2)
      stage_f16<BNt>(Bs[buf], (const f16*)B + (size_t)n0 * ldb + k0, ldb, w, lane);
    else
      rb.load((const float*)B + (size_t)n0 * ldb + k0, ldb, tid);
  };
  auto stage_write = [&](int buf) {
    if constexpr (sizeof(TA) == 4) ra.write(As[buf], tid);
    if constexpr (sizeof(TB) == 4) rb.write(Bs[buf], tid);
  };
  auto compute = [&](int buf) {
    const int fr = lane & 15, q = lane >> 4;
#pragma unroll
    for (int kk = 0; kk < 2; kk++) {
      f16x8 af[MF], bf[NF];
#pragma unroll
      for (int i = 0; i < MF; i++) {
        const int r = wr * (BMt / 2) + i * 16 + fr;
        const int slot = (kk * 4 + q) ^ (r & 7);
        af[i] = *(const f16x8*)&As[buf][r][slot * 8];
      }
#pragma unroll
      for (int j = 0; j < NF; j++) {
        const int r = wc * (BNt / 2) + j * 16 + fr;
        const int slot = (kk * 4 + q) ^ (r & 7);
        bf[j] = *(const f16x8*)&Bs[buf][r][slot * 8];
      }
#pragma unroll
      for (int i = 0; i < MF; i++)
#pragma unroll
        for (int j = 0; j < NF; j++)
          acc[i][j] = __builtin_amdgcn_mfma_f32_16x16x32_f16(af[i], bf[j], acc[i][j], 0, 0, 0);
    }
  };

  stage_issue(0, 0);
  stage_write(0);
  __syncthreads();

  const int KT = K / BK;
  for (int kt = 0; kt < KT; kt++) {
    const int cur = kt & 1, nxt = cur ^ 1;
    if (kt + 1 < KT) stage_issue(nxt, (kt + 1) * BK);   // loads fly during compute
    compute(cur);
    if (kt + 1 < KT) stage_write(nxt);                  // f32 path: cvt + ds_write late
    __syncthreads();
  }

  // epilogue: D layout col = lane&15, row = (lane>>4)*4 + r
  const int fr = lane & 15;
  const int rg = (lane >> 4) << 2;
#pragma unroll
  for (int i = 0; i < MF; i++) {
#pragma unroll
    for (int j = 0; j < NF; j++) {
      const int col = n0 + wc * (BNt / 2) + j * 16 + fr;
      float bv = 0.f;
      if constexpr (BIAS) bv = bias[col];
#pragma unroll
      for (int r = 0; r < 4; r++) {
        const int row = m0 + wr * (BMt / 2) + i * 16 + rg + r;
        float v = acc[i][j][r] + bv;
        if constexpr (RELU) v = fmaxf(v, 0.f);
        C[(size_t)row * ldc + col] = (TC)v;
      }
    }
  }
}

// f32 -> fp16 vector copy (8 elems/thread)
__global__ __launch_bounds__(256)
void copy_f32_f16(const float* __restrict__ in, f16* __restrict__ o)
{
  const size_t i = ((size_t)blockIdx.x * 256 + threadIdx.x) * 8;
  const float4 a = ((const float4*)(in + i))[0];
  const float4 b = ((const float4*)(in + i))[1];
  f16x8 v;
  v[0] = (f16)a.x; v[1] = (f16)a.y; v[2] = (f16)a.z; v[3] = (f16)a.w;
  v[4] = (f16)b.x; v[5] = (f16)b.y; v[6] = (f16)b.z; v[7] = (f16)b.w;
  *(f16x8*)(o + i) = v;
}

// bT[row] = dot(x1[row, :1024], bias)  (exact f32; 1 row per wave, 4 rows/block)
__global__ __launch_bounds__(256)
void bias_dot(const float* __restrict__ x1, const float* __restrict__ bias,
              float* __restrict__ bT)
{
  const int row  = blockIdx.x * 4 + (threadIdx.x >> 6);
  const int lane = threadIdx.x & 63;
  const float4* r = (const float4*)(x1 + (size_t)row * 1024);
  const float4* bb = (const float4*)bias;
  float acc = 0.f;
#pragma unroll
  for (int j = 0; j < 4; j++) {
    const float4 a = r[lane + j * 64];
    const float4 b = bb[lane + j * 64];
    acc += a.x * b.x + a.y * b.y + a.z * b.z + a.w * b.w;
  }
#pragma unroll
  for (int off = 32; off > 0; off >>= 1) acc += __shfl_xor(acc, off);
  if (lane == 0) bT[row] = acc;
}

// ---------------------------------------------------------------------------
// Row softmax over 2048 f32 scores; writes P fp16 packed into first 4KB of row.
// ---------------------------------------------------------------------------
__global__ __launch_bounds__(256)
void softmax_rows(float* __restrict__ S)
{
  float* row = S + (size_t)blockIdx.x * 2048;
  const int t = threadIdx.x;
  const float4 v0 = ((const float4*)row)[t];
  const float4 v1 = ((const float4*)row)[t + 256];

  float m = fmaxf(fmaxf(fmaxf(v0.x, v0.y), fmaxf(v0.z, v0.w)),
                  fmaxf(fmaxf(v1.x, v1.y), fmaxf(v1.z, v1.w)));
#pragma unroll
  for (int off = 32; off > 0; off >>= 1) m = fmaxf(m, __shfl_xor(m, off));
  __shared__ float red[8];
  if ((t & 63) == 0) red[t >> 6] = m;
  __syncthreads();
  m = fmaxf(fmaxf(red[0], red[1]), fmaxf(red[2], red[3]));

  float e0 = __expf(v0.x - m), e1 = __expf(v0.y - m), e2 = __expf(v0.z - m), e3 = __expf(v0.w - m);
  float e4 = __expf(v1.x - m), e5 = __expf(v1.y - m), e6 = __expf(v1.z - m), e7 = __expf(v1.w - m);
  float s = ((e0 + e1) + (e2 + e3)) + ((e4 + e5) + (e6 + e7));
#pragma unroll
  for (int off = 32; off > 0; off >>= 1) s += __shfl_xor(s, off);
  if ((t & 63) == 0) red[4 + (t >> 6)] = s;
  __syncthreads();
  const float inv = 1.f / (red[4] + red[5] + red[6] + red[7]);

  f16x4 o0, o1;
  o0[0] = (f16)(e0 * inv); o0[1] = (f16)(e1 * inv); o0[2] = (f16)(e2 * inv); o0[3] = (f16)(e3 * inv);
  o1[0] = (f16)(e4 * inv); o1[1] = (f16)(e5 * inv); o1[2] = (f16)(e6 * inv); o1[3] = (f16)(e7 * inv);
  f16x4* orow = (f16x4*)row;
  orow[t]       = o0;
  orow[t + 256] = o1;
}

// ---------------------------------------------------------------------------
extern "C" void kernel_launch(void* const* d_in, const int* in_sizes, int n_in,
                              void* d_out, int out_size, void* d_ws, size_t ws_size,
                              hipStream_t stream)
{
  const float* x1   = (const float*)d_in[0];
  const float* x2   = (const float*)d_in[1];
  const float* U    = (const float*)d_in[2];
  const float* bias = (const float*)d_in[3];
  const float* fcw  = (const float*)d_in[4];
  const float* fcb  = (const float*)d_in[5];
  float* out = (float*)d_out;

  const int S = 2048, D = 1024, E = 512, B = 8;
  const int SC = 1024;
  const size_t MB = 1ull << 20;

  // ws: Uh 2 | Fh 1 | W2 4 | W1T 2 | bT .0625 | Sb 8  = 17.06 MB (ws>=19 proven)
  char* w = (char*)d_ws;
  f16*   Uh  = (f16*)(w);
  f16*   Fh  = (f16*)(w + 2 * MB);
  f16*   W2  = (f16*)(w + 3 * MB);
  f16*   W1T = (f16*)(w + 7 * MB);
  float* bT  = (float*)(w + 9 * MB);
  float* Sb  = (float*)(w + 9 * MB + 256 * 1024);

  // X2h_all overlays d_out (8*2048*1024 f16 == 8*2048*512 f32 exactly).
  // K4' overwrites batch-b rows only AFTER K2 consumed them (stream-ordered).
  f16* X2h = (f16*)d_out;

  // one-time conversions (numerically identical to per-tile reg-stage cvt)
  copy_f32_f16<<<dim3(B * S * D / 2048), 256, 0, stream>>>(x2, X2h);
  copy_f32_f16<<<dim3(D * D / 2048), 256, 0, stream>>>(U, Uh);
  copy_f32_f16<<<dim3(E * D / 2048), 256, 0, stream>>>(fcw, Fh);
  bias_dot<<<dim3(B * S / 4), 256, 0, stream>>>(x1, bias, bT);

  for (int b = 0; b < B; b++) {
    const float* x1b = x1 + (size_t)b * S * D;
    const f16*   X2b = X2h + (size_t)b * S * D;

    // K0: W2[t][d] = sum_e x1b[t,e] Uh[d,e]  (A=x1b f32 reg, B=Uh f16 gload)
    // grid (32,16) = 512 blocks, 2/CU
    gemm_tn<64, 64, float, f16, false, false, f16><<<dim3(S / 64, D / 64), 256, 0, stream>>>(
        x1b, D, Uh, D, W2, D, nullptr, D);

    // W1T[e][t] = sum_d Fh[e,d] x1b[t,d]  (A=Fh f16 gload, B=x1b f32 reg)
    // grid (8,32) = 256 blocks
    gemm_tn<64, 64, f16, float, false, false, f16><<<dim3(E / 64, S / 64), 256, 0, stream>>>(
        Fh, D, x1b, D, W1T, S, nullptr, D);

    for (int s0 = 0; s0 < S; s0 += SC) {
      // K2: Sb[s][t] = sum_d X2b[s0+s,d] W2[t,d] + bT[t]  (f16 x f16)
      // grid (16,32) = 512 blocks, 2/CU
      gemm_tn<64, 64, f16, f16, true, false, float><<<dim3(SC / 64, S / 64), 256, 0, stream>>>(
          X2b + (size_t)s0 * D, D, W2, D, Sb, S, bT + (size_t)b * S, D);
      // K3: softmax -> P f16 packed (lda 2S)
      softmax_rows<<<dim3(SC), 256, 0, stream>>>(Sb);
      // K4': out rows [s0,s0+SC) = relu(P @ W1T^T + fcb)  (K = t = 2048)
      gemm_tn<64, 64, f16, f16, true, true, float><<<dim3(SC / 64, E / 64), 256, 0, stream>>>(
          (const f16*)Sb, 2 * S, W1T, S, out + ((size_t)b * S + s0) * E, E, fcb, S);
    }
  }
}

// Round 7
// 829.150 us; speedup vs baseline: 1.0930x; 1.0930x over previous
//
#include <hip/hip_runtime.h>
#include <hip/hip_fp16.h>
#include <cstddef>
#include <cstdint>

typedef _Float16 f16;
typedef _Float16 f16x8 __attribute__((ext_vector_type(8)));
typedef _Float16 f16x4 __attribute__((ext_vector_type(4)));
typedef float    f32x4 __attribute__((ext_vector_type(4)));

// async 16B global->LDS (linear LDS dest = wave-uniform base + lane*16)
__device__ __forceinline__ void gload16(const void* g, void* lds) {
  __builtin_amdgcn_global_load_lds(
      (const __attribute__((address_space(1))) unsigned int*)g,
      (__attribute__((address_space(3))) unsigned int*)lds, 16, 0, 0);
}

// Stage an [R x BKt] fp16 tile via global_load_lds. LDS row r holds global
// 8-elem slot s at slot s^(r&7) (rule-21 both-sides swizzle: source address
// pre-swizzled, reader XORs identically; XOR hits only low 3 slot bits so
// it is bijective for 8- or 16-slot rows).
template<int R, int BKt>
__device__ __forceinline__ void stage_f16(f16 (*buf)[BKt], const f16* __restrict__ src,
                                          int ld, int w, int lane) {
  constexpr int RPL = 512 / BKt;        // rows covered per 1KB wave-load
  constexpr int SPR = BKt / 8;          // 8-elem slots per row
  constexpr int LPW = R * BKt / 2048;   // wave-loads per wave
#pragma unroll
  for (int i = 0; i < LPW; i++) {
    const int rbase = (w * LPW + i) * RPL;          // wave-uniform
    const int r     = rbase + lane / SPR;
    const int gslot = (lane % SPR) ^ (r & 7);
    gload16(src + (size_t)r * ld + gslot * 8, &buf[rbase][0]);
  }
}

// ---------------------------------------------------------------------------
// TN GEMM, double-buffered, all-fp16: C[M][N] = A[M][K] @ B[N][K]^T
// (+bias[n]) (+relu). 256 thr = 4 waves (2x2); mfma_f32_16x16x32_f16.
// Chunked bijective XCD swizzle on (bx,by); requires nxy % 8 == 0.
// Grids here are <=256 blocks (1 block/CU), so BKt=128's 96KB LDS costs no
// occupancy and halves barrier count (32 MFMA per barrier).
// ---------------------------------------------------------------------------
template<int BMt, int BNt, int BKt, bool BIAS, bool RELU, typename TC>
__global__ __launch_bounds__(256, 1)
void gemm_tn(const f16* __restrict__ A, int lda,
             const f16* __restrict__ B, int ldb,
             TC* __restrict__ C, int ldc,
             const float* __restrict__ bias, int K)
{
  constexpr int MF = BMt / 32;
  constexpr int NF = BNt / 32;
  constexpr int KS = BKt / 32;          // MFMA k-steps per tile
  __shared__ f16 As[2][BMt][BKt];
  __shared__ f16 Bs[2][BNt][BKt];
  const int tid  = threadIdx.x;
  const int lane = tid & 63;
  const int w    = tid >> 6;
  const int wr   = w >> 1, wc = w & 1;

  const int gx = gridDim.x, nxy = gx * gridDim.y;
  int lin = blockIdx.y * gx + blockIdx.x;
  lin = (lin & 7) * (nxy >> 3) + (lin >> 3);
  const int m0 = (lin % gx) * BMt;
  const int n0 = (lin / gx) * BNt;

  f32x4 acc[MF][NF] = {};

  auto stage = [&](int buf, int k0) {
    stage_f16<BMt, BKt>(As[buf], A + (size_t)m0 * lda + k0, lda, w, lane);
    stage_f16<BNt, BKt>(Bs[buf], B + (size_t)n0 * ldb + k0, ldb, w, lane);
  };
  auto compute = [&](int buf) {
    const int fr = lane & 15, q = lane >> 4;
#pragma unroll
    for (int kk = 0; kk < KS; kk++) {
      f16x8 af[MF], bf[NF];
#pragma unroll
      for (int i = 0; i < MF; i++) {
        const int r = wr * (BMt / 2) + i * 16 + fr;
        const int slot = (kk * 4 + q) ^ (r & 7);   // XOR only low 3 bits
        af[i] = *(const f16x8*)&As[buf][r][slot * 8];
      }
#pragma unroll
      for (int j = 0; j < NF; j++) {
        const int r = wc * (BNt / 2) + j * 16 + fr;
        const int slot = (kk * 4 + q) ^ (r & 7);
        bf[j] = *(const f16x8*)&Bs[buf][r][slot * 8];
      }
#pragma unroll
      for (int i = 0; i < MF; i++)
#pragma unroll
        for (int j = 0; j < NF; j++)
          acc[i][j] = __builtin_amdgcn_mfma_f32_16x16x32_f16(af[i], bf[j], acc[i][j], 0, 0, 0);
    }
  };

  stage(0, 0);
  __syncthreads();

  const int KT = K / BKt;
  for (int kt = 0; kt < KT; kt++) {
    const int cur = kt & 1, nxt = cur ^ 1;
    if (kt + 1 < KT) stage(nxt, (kt + 1) * BKt);   // loads fly during compute
    compute(cur);
    __syncthreads();                               // drains vmcnt, flips buffers
  }

  // epilogue: D layout col = lane&15, row = (lane>>4)*4 + r
  const int fr = lane & 15;
  const int rg = (lane >> 4) << 2;
#pragma unroll
  for (int i = 0; i < MF; i++) {
#pragma unroll
    for (int j = 0; j < NF; j++) {
      const int col = n0 + wc * (BNt / 2) + j * 16 + fr;
      float bv = 0.f;
      if constexpr (BIAS) bv = bias[col];
#pragma unroll
      for (int r = 0; r < 4; r++) {
        const int row = m0 + wr * (BMt / 2) + i * 16 + rg + r;
        float v = acc[i][j][r] + bv;
        if constexpr (RELU) v = fmaxf(v, 0.f);
        C[(size_t)row * ldc + col] = (TC)v;
      }
    }
  }
}

// f32 -> fp16 vector copy (8 elems/thread)
__global__ __launch_bounds__(256)
void copy_f32_f16(const float* __restrict__ in, f16* __restrict__ o)
{
  const size_t i = ((size_t)blockIdx.x * 256 + threadIdx.x) * 8;
  const float4 a = ((const float4*)(in + i))[0];
  const float4 b = ((const float4*)(in + i))[1];
  f16x8 v;
  v[0] = (f16)a.x; v[1] = (f16)a.y; v[2] = (f16)a.z; v[3] = (f16)a.w;
  v[4] = (f16)b.x; v[5] = (f16)b.y; v[6] = (f16)b.z; v[7] = (f16)b.w;
  *(f16x8*)(o + i) = v;
}

// bT[row] = dot(x1[row, :1024], bias)  (exact f32; 1 row per wave)
__global__ __launch_bounds__(256)
void bias_dot(const float* __restrict__ x1, const float* __restrict__ bias,
              float* __restrict__ bT)
{
  const int row  = blockIdx.x * 4 + (threadIdx.x >> 6);
  const int lane = threadIdx.x & 63;
  const float4* r = (const float4*)(x1 + (size_t)row * 1024);
  const float4* bb = (const float4*)bias;
  float acc = 0.f;
#pragma unroll
  for (int j = 0; j < 4; j++) {
    const float4 a = r[lane + j * 64];
    const float4 b = bb[lane + j * 64];
    acc += a.x * b.x + a.y * b.y + a.z * b.z + a.w * b.w;
  }
#pragma unroll
  for (int off = 32; off > 0; off >>= 1) acc += __shfl_xor(acc, off);
  if (lane == 0) bT[row] = acc;
}

// ---------------------------------------------------------------------------
// Row softmax over 2048 f32 scores; writes P fp16 packed into first 4KB of row.
// ---------------------------------------------------------------------------
__global__ __launch_bounds__(256)
void softmax_rows(float* __restrict__ S)
{
  float* row = S + (size_t)blockIdx.x * 2048;
  const int t = threadIdx.x;
  const float4 v0 = ((const float4*)row)[t];
  const float4 v1 = ((const float4*)row)[t + 256];

  float m = fmaxf(fmaxf(fmaxf(v0.x, v0.y), fmaxf(v0.z, v0.w)),
                  fmaxf(fmaxf(v1.x, v1.y), fmaxf(v1.z, v1.w)));
#pragma unroll
  for (int off = 32; off > 0; off >>= 1) m = fmaxf(m, __shfl_xor(m, off));
  __shared__ float red[8];
  if ((t & 63) == 0) red[t >> 6] = m;
  __syncthreads();
  m = fmaxf(fmaxf(red[0], red[1]), fmaxf(red[2], red[3]));

  float e0 = __expf(v0.x - m), e1 = __expf(v0.y - m), e2 = __expf(v0.z - m), e3 = __expf(v0.w - m);
  float e4 = __expf(v1.x - m), e5 = __expf(v1.y - m), e6 = __expf(v1.z - m), e7 = __expf(v1.w - m);
  float s = ((e0 + e1) + (e2 + e3)) + ((e4 + e5) + (e6 + e7));
#pragma unroll
  for (int off = 32; off > 0; off >>= 1) s += __shfl_xor(s, off);
  if ((t & 63) == 0) red[4 + (t >> 6)] = s;
  __syncthreads();
  const float inv = 1.f / (red[4] + red[5] + red[6] + red[7]);

  f16x4 o0, o1;
  o0[0] = (f16)(e0 * inv); o0[1] = (f16)(e1 * inv); o0[2] = (f16)(e2 * inv); o0[3] = (f16)(e3 * inv);
  o1[0] = (f16)(e4 * inv); o1[1] = (f16)(e5 * inv); o1[2] = (f16)(e6 * inv); o1[3] = (f16)(e7 * inv);
  f16x4* orow = (f16x4*)row;
  orow[t]       = o0;
  orow[t + 256] = o1;
}

// ---------------------------------------------------------------------------
extern "C" void kernel_launch(void* const* d_in, const int* in_sizes, int n_in,
                              void* d_out, int out_size, void* d_ws, size_t ws_size,
                              hipStream_t stream)
{
  const float* x1   = (const float*)d_in[0];
  const float* x2   = (const float*)d_in[1];
  const float* U    = (const float*)d_in[2];
  const float* bias = (const float*)d_in[3];
  const float* fcw  = (const float*)d_in[4];
  const float* fcb  = (const float*)d_in[5];
  float* out = (float*)d_out;

  const int S = 2048, D = 1024, E = 512, B = 8;
  const int SC = 1024;
  const size_t MB = 1ull << 20;
  const size_t KB64 = 64 * 1024;

  // ws: W2 4 | W1T 2 | bT 64K | Sb 8 (X1h overlays first 4MB) | Uh 2 | Fh 1
  //   = 17.06 MB  (ws >= 19 MB proven in R1)
  char* w = (char*)d_ws;
  f16*   W2  = (f16*)(w);
  f16*   W1T = (f16*)(w + 4 * MB);
  float* bT  = (float*)(w + 6 * MB);
  float* Sb  = (float*)(w + 6 * MB + KB64);
  f16*   X1h = (f16*)(w + 6 * MB + KB64);            // dies when K2 writes Sb
  f16*   Uh  = (f16*)(w + 14 * MB + KB64);
  f16*   Fh  = (f16*)(w + 16 * MB + KB64);

  // X2h_all overlays d_out (8*2048*1024 f16 == 8*2048*512 f32 exactly).
  // K4' overwrites batch-b rows only AFTER K2 consumed them (stream-ordered).
  f16* X2h = (f16*)d_out;

  // one-time conversions (identical rounding to per-tile staging cvt)
  copy_f32_f16<<<dim3(B * S * D / 2048), 256, 0, stream>>>(x2, X2h);
  copy_f32_f16<<<dim3(D * D / 2048), 256, 0, stream>>>(U, Uh);
  copy_f32_f16<<<dim3(E * D / 2048), 256, 0, stream>>>(fcw, Fh);
  bias_dot<<<dim3(B * S / 4), 256, 0, stream>>>(x1, bias, bT);

  for (int b = 0; b < B; b++) {
    const float* x1b = x1 + (size_t)b * S * D;
    const f16*   X2b = X2h + (size_t)b * S * D;

    // x1b -> X1h fp16 (consumed by K0 + W1T before K2 overwrites the region)
    copy_f32_f16<<<dim3(S * D / 2048), 256, 0, stream>>>(x1b, X1h);

    // K0: W2[t][d] = sum_e X1h[t,e] Uh[d,e]   grid (32,8)=256, 1/CU
    gemm_tn<64, 128, 128, false, false, f16><<<dim3(S / 64, D / 128), 256, 0, stream>>>(
        X1h, D, Uh, D, W2, D, nullptr, D);

    // W1T[e][t] = sum_d Fh[e,d] X1h[t,d]      grid (8,16)=128
    gemm_tn<64, 128, 128, false, false, f16><<<dim3(E / 64, S / 128), 256, 0, stream>>>(
        Fh, D, X1h, D, W1T, S, nullptr, D);

    for (int s0 = 0; s0 < S; s0 += SC) {
      // K2: Sb[s][t] = sum_d X2b[s0+s,d] W2[t,d] + bT[t]  grid (16,16)=256
      gemm_tn<64, 128, 128, true, false, float><<<dim3(SC / 64, S / 128), 256, 0, stream>>>(
          X2b + (size_t)s0 * D, D, W2, D, Sb, S, bT + (size_t)b * S, D);
      // K3: softmax -> P fp16 packed (lda 2S)
      softmax_rows<<<dim3(SC), 256, 0, stream>>>(Sb);
      // K4': out rows [s0,s0+SC) = relu(P @ W1T^T + fcb)  (K=t=2048) grid (16,8)=128
      gemm_tn<64, 64, 128, true, true, float><<<dim3(SC / 64, E / 64), 256, 0, stream>>>(
          (const f16*)Sb, 2 * S, W1T, S, out + ((size_t)b * S + s0) * E, E, fcb, S);
    }
  }
}